// Round 8
// baseline (564.458 us; speedup 1.0000x reference)
//
#include <hip/hip_runtime.h>

typedef unsigned long long ull;

#define NB    16      // batches
#define NPTS  65536   // points per batch
#define NSEED 40      // seeds
#define BPB   4       // blocks per batch (4x fewer exchange participants)
#define TPB   1024    // threads per block (16 waves)
#define NW    16      // waves per block
#define PPT   16      // points per thread = NPTS/(BPB*TPB)
#define R2    0.0025f // RADIUS^2
#define PAYLOAD 0xFFFFFFFFFFFFull

// pack (value, index): unsigned max == (max value, then smallest index)
// idx < 65536 fits 16 bits; complement for smallest-index tie-break
__device__ __forceinline__ ull packdi(float v, int idx) {
  return ((ull)__float_as_uint(v) << 16) | (ull)((unsigned)(idx ^ 0xFFFF) & 0xFFFFu);
}

__global__ __launch_bounds__(TPB, 4) void fps_den_kernel(
    const float* __restrict__ pcs, ull* __restrict__ slots, float* __restrict__ pden)
{
  const int beta = blockIdx.x >> 2;   // batch
  const int blk  = blockIdx.x & 3;    // block within batch
  const int tid  = threadIdx.x;
  const int lane = tid & 63;
  const int wav  = tid >> 6;
  const float* __restrict__ base = pcs + (size_t)beta * (NPTS * 3);

  __shared__ ull   sRedP[2][NW];                    // parity-buffered wave winners
  __shared__ float sRedX[2][NW], sRedY[2][NW], sRedZ[2][NW];
  __shared__ float sWx[2], sWy[2], sWz[2];          // parity-buffered round winner
  __shared__ float sDen[NW][NSEED];                 // per-wave density partials

  // register-resident points + running min-distance (16 pts x 4 = 64 VGPRs)
  float px[PPT], py[PPT], pz[PPT], dist[PPT];
#pragma unroll
  for (int j = 0; j < PPT; ++j) {
    int n = blk * (TPB * PPT) + j * TPB + tid;
    px[j] = base[n * 3 + 0];
    py[j] = base[n * 3 + 1];
    pz[j] = base[n * 3 + 2];
    dist[j] = 1e10f;
  }

  float cx = base[0], cy = base[1], cz = base[2];   // seed 0 = point 0

  // record layout: [beta][parity][blk][word], word w = (gen<<48) | payload_w
  //   w0: dist/idx packed   w1: x bits   w2: y bits   w3: z bits
  ull* myslots = slots + (size_t)beta * (2 * BPB * 4);

  for (int k = 0; k < NSEED - 1; ++k) {
    // ---- min-update + local argmax for next seed ----
    ull bestp = 0; float bx = 0.f, by = 0.f, bz = 0.f;
#pragma unroll
    for (int j = 0; j < PPT; ++j) {
      float dx = px[j] - cx, dy = py[j] - cy, dz = pz[j] - cz;
      // match numpy: round each square, sum as (d0+d1)+d2, no FMA contraction
      float d  = __fadd_rn(__fadd_rn(__fmul_rn(dx, dx), __fmul_rn(dy, dy)),
                           __fmul_rn(dz, dz));
      float nd = fminf(dist[j], d);
      dist[j]  = nd;
      int n    = blk * (TPB * PPT) + j * TPB + tid;
      ull p    = packdi(nd, n);
      if (p > bestp) { bestp = p; bx = px[j]; by = py[j]; bz = pz[j]; }
    }
#pragma unroll
    for (int o = 32; o > 0; o >>= 1) {
      ull   q  = __shfl_xor(bestp, o, 64);
      float qx = __shfl_xor(bx, o, 64);
      float qy = __shfl_xor(by, o, 64);
      float qz = __shfl_xor(bz, o, 64);
      if (q > bestp) { bestp = q; bx = qx; by = qy; bz = qz; }
    }
    if (lane == 0) {
      sRedP[k & 1][wav] = bestp;
      sRedX[k & 1][wav] = bx; sRedY[k & 1][wav] = by; sRedZ[k & 1][wav] = bz;
    }
    __syncthreads();   // barrier 1

    const ull gen = (ull)(k + 1);
    const ull g48 = gen << 48;
    ull* arr = myslots + (size_t)((k + 1) & 1) * (BPB * 4);

    // ---- density for CURRENT seed c_k, overlapped with the exchange ----
    float da = 0.f;
    if (wav != 0) {
#pragma unroll
      for (int j = 0; j < PPT; ++j) {
        float dx = px[j] - cx, dy = py[j] - cy, dz = pz[j] - cz;
        float d  = dx * dx + dy * dy + dz * dz;
        da += fmaxf(R2 - d, 0.f);
      }
#pragma unroll
      for (int o = 32; o > 0; o >>= 1) da += __shfl_xor(da, o, 64);
      if (lane == 0) sDen[wav][k] = da;
    } else {
      // cross-wave argmax (lanes 0..15), carrying coords
      ull   rp = (lane < NW) ? sRedP[k & 1][lane] : 0;
      float rx = (lane < NW) ? sRedX[k & 1][lane] : 0.f;
      float ry = (lane < NW) ? sRedY[k & 1][lane] : 0.f;
      float rz = (lane < NW) ? sRedZ[k & 1][lane] : 0.f;
#pragma unroll
      for (int o = 8; o > 0; o >>= 1) {
        ull   q  = __shfl_xor(rp, o, 64);
        float qx = __shfl_xor(rx, o, 64);
        float qy = __shfl_xor(ry, o, 64);
        float qz = __shfl_xor(rz, o, 64);
        if (q > rp) { rp = q; rx = qx; ry = qy; rz = qz; }
      }
      // publish 32-B record via lanes 0..3, ONE plain relaxed store instruction
      ull rec = g48 | (rp & PAYLOAD);
      if (lane == 1) rec = g48 | (ull)__float_as_uint(rx);
      if (lane == 2) rec = g48 | (ull)__float_as_uint(ry);
      if (lane == 3) rec = g48 | (ull)__float_as_uint(rz);
      if (lane < 4)
        __hip_atomic_store(&arr[blk * 4 + lane], rec,
                           __ATOMIC_RELAXED, __HIP_MEMORY_SCOPE_AGENT);

      // wave 0's own density while the store flies
#pragma unroll
      for (int j = 0; j < PPT; ++j) {
        float dx = px[j] - cx, dy = py[j] - cy, dz = pz[j] - cz;
        float d  = dx * dx + dy * dy + dz * dz;
        da += fmaxf(R2 - d, 0.f);
      }
#pragma unroll
      for (int o = 32; o > 0; o >>= 1) da += __shfl_xor(da, o, 64);
      if (lane == 0) sDen[0][k] = da;

      // poll: 4 slots x 4 words = 16 words -> lane i (i<16) watches word i.
      // entire exchange state arrives in ONE wave load per iteration.
      for (;;) {
        ull v = 0;
        if (lane < BPB * 4)
          v = __hip_atomic_load(&arr[lane], __ATOMIC_RELAXED,
                                __HIP_MEMORY_SCOPE_AGENT);
        int ok = (lane < BPB * 4) ? (int)((v >> 48) == gen) : 1;
        if (__all(ok)) {
          ull pl = ((lane < BPB * 4) && ((lane & 3) == 0)) ? (v & PAYLOAD) : 0;
          ull m = pl;
#pragma unroll
          for (int o = 32; o > 0; o >>= 1) {
            ull q = __shfl_xor(m, o, 64);
            m = m > q ? m : q;
          }
          int has = (pl == m) && (pl != 0);
          ull bal = __ballot(has);
          int src = __ffsll((long long)bal) - 1;   // winner's word-0 lane
          float f  = __uint_as_float((unsigned)(v & 0xFFFFFFFFull));
          float wx = __shfl(f, src + 1, 64);
          float wy = __shfl(f, src + 2, 64);
          float wz = __shfl(f, src + 3, 64);
          if (lane == 0) {
            sWx[k & 1] = wx; sWy[k & 1] = wy; sWz[k & 1] = wz;
          }
          break;
        }
      }
    }
    __syncthreads();   // barrier 2: winner published
    cx = sWx[k & 1]; cy = sWy[k & 1]; cz = sWz[k & 1];
  }

  // ---- density for the last seed (c_39) ----
  {
    float a = 0.f;
#pragma unroll
    for (int j = 0; j < PPT; ++j) {
      float dx = px[j] - cx, dy = py[j] - cy, dz = pz[j] - cz;
      float d  = dx * dx + dy * dy + dz * dz;
      a += fmaxf(R2 - d, 0.f);
    }
#pragma unroll
    for (int o = 32; o > 0; o >>= 1) a += __shfl_xor(a, o, 64);
    if (lane == 0) sDen[wav][NSEED - 1] = a;
  }
  __syncthreads();

  if (tid < NSEED) {   // per-block density partial, plain stores
    float t = 0.f;
#pragma unroll
    for (int w = 0; w < NW; ++w) t += sDen[w][tid];
    pden[((size_t)beta * BPB + blk) * NSEED + tid] = t;
  }
}

__global__ void var_kernel(const float* __restrict__ pden, float* __restrict__ out) {
  __shared__ float sD[NB][NSEED];
  __shared__ float sV[NB];
  int t = threadIdx.x;
  if (t < NB * NSEED) {
    int beta = t / NSEED, s = t - beta * NSEED;
    float a = 0.f;
#pragma unroll
    for (int b = 0; b < BPB; ++b) a += pden[((size_t)beta * BPB + b) * NSEED + s];
    sD[beta][s] = a;
  }
  __syncthreads();
  if (t < NB) {
    float m = 0.f;
    for (int s = 0; s < NSEED; ++s) m += sD[t][s];
    m /= (float)NSEED;
    float q = 0.f;
    for (int s = 0; s < NSEED; ++s) { float d = sD[t][s] - m; q += d * d; }
    sV[t] = q / (float)(NSEED - 1);   // ddof=1
  }
  __syncthreads();
  if (t == 0) {
    float v = 0.f;
    for (int i = 0; i < NB; ++i) v += sV[i];
    out[0] = v / (float)NB;
  }
}

extern "C" void kernel_launch(void* const* d_in, const int* in_sizes, int n_in,
                              void* d_out, int out_size, void* d_ws, size_t ws_size,
                              hipStream_t stream) {
  const float* pcs = (const float*)d_in[0];
  float* out  = (float*)d_out;
  float* pden = (float*)d_ws;                       // 16*4*40*4 = 10240 B
  ull*   slots = (ull*)((char*)d_ws + 10240);       // 16*2*4*4*8 = 4096 B
  // slots need no init: poisoned 0xAA.. gives gen tag 0xAAAA, never in 1..39
  // pden needs no init: every entry written unconditionally each launch

  // 64 blocks of 16 waves: trivially co-resident on 256 CUs (latency-bound
  // phase needs residency for the spin loop, not throughput)
  fps_den_kernel<<<dim3(NB * BPB), dim3(TPB), 0, stream>>>(pcs, slots, pden);
  var_kernel<<<dim3(1), dim3(TPB), 0, stream>>>(pden, out);
}

// Round 9
// 554.522 us; speedup vs baseline: 1.0179x; 1.0179x over previous
//
#include <hip/hip_runtime.h>

typedef unsigned long long ull;

#define NB    16      // batches
#define NPTS  65536   // points per batch
#define NSEED 40      // seeds
#define BPB   4       // blocks per batch (few exchange participants)
#define TPB   1024    // threads per block (16 waves)
#define NW    16      // waves per block
#define PPT   16      // points per thread = NPTS/(BPB*TPB)
#define R2    0.0025f // RADIUS^2
#define PAYLOAD 0xFFFFFFFFFFFFull

// pack (value, index): unsigned max == (max value, then smallest index)
__device__ __forceinline__ ull packdi(float v, int idx) {
  return ((ull)__float_as_uint(v) << 16) | (ull)((unsigned)(idx ^ 0xFFFF) & 0xFFFFu);
}

// launch_bounds(1024, 1): do NOT cap VGPRs below the ~100 live registers
// (R8's (1024,4) clamped to 64 VGPR -> spilled px/py/pz/dist to scratch,
//  WRITE_SIZE 352KB->24MB, 3.3x regression)
__global__ __launch_bounds__(TPB, 1) void fps_den_kernel(
    const float* __restrict__ pcs, ull* __restrict__ slots, float* __restrict__ pden)
{
  const int beta = blockIdx.x >> 2;   // batch
  const int blk  = blockIdx.x & 3;    // block within batch
  const int tid  = threadIdx.x;
  const int lane = tid & 63;
  const int wav  = tid >> 6;
  const float* __restrict__ base = pcs + (size_t)beta * (NPTS * 3);

  __shared__ ull   sRedP[2][NW];                    // parity-buffered wave winners
  __shared__ float sRedX[2][NW], sRedY[2][NW], sRedZ[2][NW];
  __shared__ float sWx[2], sWy[2], sWz[2];          // parity-buffered round winner
  __shared__ float sDen[NW][NSEED];                 // per-wave density partials

  // register-resident points + running min-distance (16 pts x 4 = 64 VGPRs)
  float px[PPT], py[PPT], pz[PPT], dist[PPT];
#pragma unroll
  for (int j = 0; j < PPT; ++j) {
    int n = blk * (TPB * PPT) + j * TPB + tid;
    px[j] = base[n * 3 + 0];
    py[j] = base[n * 3 + 1];
    pz[j] = base[n * 3 + 2];
    dist[j] = 1e10f;
  }

  float cx = base[0], cy = base[1], cz = base[2];   // seed 0 = point 0

  // record layout: [beta][parity][blk][word], word w = (gen<<48) | payload_w
  //   w0: dist/idx packed   w1: x bits   w2: y bits   w3: z bits
  ull* myslots = slots + (size_t)beta * (2 * BPB * 4);

  for (int k = 0; k < NSEED - 1; ++k) {
    // ---- min-update + local argmax for next seed ----
    ull bestp = 0; float bx = 0.f, by = 0.f, bz = 0.f;
#pragma unroll
    for (int j = 0; j < PPT; ++j) {
      float dx = px[j] - cx, dy = py[j] - cy, dz = pz[j] - cz;
      // match numpy: round each square, sum as (d0+d1)+d2, no FMA contraction
      float d  = __fadd_rn(__fadd_rn(__fmul_rn(dx, dx), __fmul_rn(dy, dy)),
                           __fmul_rn(dz, dz));
      float nd = fminf(dist[j], d);
      dist[j]  = nd;
      int n    = blk * (TPB * PPT) + j * TPB + tid;
      ull p    = packdi(nd, n);
      if (p > bestp) { bestp = p; bx = px[j]; by = py[j]; bz = pz[j]; }
    }
#pragma unroll
    for (int o = 32; o > 0; o >>= 1) {
      ull   q  = __shfl_xor(bestp, o, 64);
      float qx = __shfl_xor(bx, o, 64);
      float qy = __shfl_xor(by, o, 64);
      float qz = __shfl_xor(bz, o, 64);
      if (q > bestp) { bestp = q; bx = qx; by = qy; bz = qz; }
    }
    if (lane == 0) {
      sRedP[k & 1][wav] = bestp;
      sRedX[k & 1][wav] = bx; sRedY[k & 1][wav] = by; sRedZ[k & 1][wav] = bz;
    }
    __syncthreads();   // barrier 1

    const ull gen = (ull)(k + 1);
    const ull g48 = gen << 48;
    ull* arr = myslots + (size_t)((k + 1) & 1) * (BPB * 4);

    // ---- density for CURRENT seed c_k, overlapped with the exchange ----
    float da = 0.f;
    if (wav != 0) {
#pragma unroll
      for (int j = 0; j < PPT; ++j) {
        float dx = px[j] - cx, dy = py[j] - cy, dz = pz[j] - cz;
        float d  = dx * dx + dy * dy + dz * dz;
        da += fmaxf(R2 - d, 0.f);
      }
#pragma unroll
      for (int o = 32; o > 0; o >>= 1) da += __shfl_xor(da, o, 64);
      if (lane == 0) sDen[wav][k] = da;
    } else {
      // cross-wave argmax (lanes 0..15), carrying coords
      ull   rp = (lane < NW) ? sRedP[k & 1][lane] : 0;
      float rx = (lane < NW) ? sRedX[k & 1][lane] : 0.f;
      float ry = (lane < NW) ? sRedY[k & 1][lane] : 0.f;
      float rz = (lane < NW) ? sRedZ[k & 1][lane] : 0.f;
#pragma unroll
      for (int o = 8; o > 0; o >>= 1) {
        ull   q  = __shfl_xor(rp, o, 64);
        float qx = __shfl_xor(rx, o, 64);
        float qy = __shfl_xor(ry, o, 64);
        float qz = __shfl_xor(rz, o, 64);
        if (q > rp) { rp = q; rx = qx; ry = qy; rz = qz; }
      }
      // publish 32-B record via lanes 0..3, ONE plain relaxed store instruction
      ull rec = g48 | (rp & PAYLOAD);
      if (lane == 1) rec = g48 | (ull)__float_as_uint(rx);
      if (lane == 2) rec = g48 | (ull)__float_as_uint(ry);
      if (lane == 3) rec = g48 | (ull)__float_as_uint(rz);
      if (lane < 4)
        __hip_atomic_store(&arr[blk * 4 + lane], rec,
                           __ATOMIC_RELAXED, __HIP_MEMORY_SCOPE_AGENT);

      // wave 0's own density while the store flies
#pragma unroll
      for (int j = 0; j < PPT; ++j) {
        float dx = px[j] - cx, dy = py[j] - cy, dz = pz[j] - cz;
        float d  = dx * dx + dy * dy + dz * dz;
        da += fmaxf(R2 - d, 0.f);
      }
#pragma unroll
      for (int o = 32; o > 0; o >>= 1) da += __shfl_xor(da, o, 64);
      if (lane == 0) sDen[0][k] = da;

      // poll: 4 slots x 4 words = 16 words -> lane i (i<16) watches word i.
      // entire exchange state arrives in ONE wave load per iteration.
      for (;;) {
        ull v = 0;
        if (lane < BPB * 4)
          v = __hip_atomic_load(&arr[lane], __ATOMIC_RELAXED,
                                __HIP_MEMORY_SCOPE_AGENT);
        int ok = (lane < BPB * 4) ? (int)((v >> 48) == gen) : 1;
        if (__all(ok)) {
          ull pl = ((lane < BPB * 4) && ((lane & 3) == 0)) ? (v & PAYLOAD) : 0;
          ull m = pl;
#pragma unroll
          for (int o = 32; o > 0; o >>= 1) {
            ull q = __shfl_xor(m, o, 64);
            m = m > q ? m : q;
          }
          int has = (pl == m) && ((lane & 3) == 0) && (lane < BPB * 4);
          ull bal = __ballot(has);
          int src = __ffsll((long long)bal) - 1;   // winner's word-0 lane
          float f  = __uint_as_float((unsigned)(v & 0xFFFFFFFFull));
          float wx = __shfl(f, src + 1, 64);
          float wy = __shfl(f, src + 2, 64);
          float wz = __shfl(f, src + 3, 64);
          if (lane == 0) {
            sWx[k & 1] = wx; sWy[k & 1] = wy; sWz[k & 1] = wz;
          }
          break;
        }
      }
    }
    __syncthreads();   // barrier 2: winner published
    cx = sWx[k & 1]; cy = sWy[k & 1]; cz = sWz[k & 1];
  }

  // ---- density for the last seed (c_39) ----
  {
    float a = 0.f;
#pragma unroll
    for (int j = 0; j < PPT; ++j) {
      float dx = px[j] - cx, dy = py[j] - cy, dz = pz[j] - cz;
      float d  = dx * dx + dy * dy + dz * dz;
      a += fmaxf(R2 - d, 0.f);
    }
#pragma unroll
    for (int o = 32; o > 0; o >>= 1) a += __shfl_xor(a, o, 64);
    if (lane == 0) sDen[wav][NSEED - 1] = a;
  }
  __syncthreads();

  if (tid < NSEED) {   // per-block density partial, plain stores
    float t = 0.f;
#pragma unroll
    for (int w = 0; w < NW; ++w) t += sDen[w][tid];
    pden[((size_t)beta * BPB + blk) * NSEED + tid] = t;
  }
}

__global__ void var_kernel(const float* __restrict__ pden, float* __restrict__ out) {
  __shared__ float sD[NB][NSEED];
  __shared__ float sV[NB];
  int t = threadIdx.x;
  if (t < NB * NSEED) {
    int beta = t / NSEED, s = t - beta * NSEED;
    float a = 0.f;
#pragma unroll
    for (int b = 0; b < BPB; ++b) a += pden[((size_t)beta * BPB + b) * NSEED + s];
    sD[beta][s] = a;
  }
  __syncthreads();
  if (t < NB) {
    float m = 0.f;
    for (int s = 0; s < NSEED; ++s) m += sD[t][s];
    m /= (float)NSEED;
    float q = 0.f;
    for (int s = 0; s < NSEED; ++s) { float d = sD[t][s] - m; q += d * d; }
    sV[t] = q / (float)(NSEED - 1);   // ddof=1
  }
  __syncthreads();
  if (t == 0) {
    float v = 0.f;
    for (int i = 0; i < NB; ++i) v += sV[i];
    out[0] = v / (float)NB;
  }
}

extern "C" void kernel_launch(void* const* d_in, const int* in_sizes, int n_in,
                              void* d_out, int out_size, void* d_ws, size_t ws_size,
                              hipStream_t stream) {
  const float* pcs = (const float*)d_in[0];
  float* out  = (float*)d_out;
  float* pden = (float*)d_ws;                       // 16*4*40*4 = 10240 B
  ull*   slots = (ull*)((char*)d_ws + 10240);       // 16*2*4*4*8 = 4096 B
  // slots need no init: poisoned 0xAA.. gives gen tag 0xAAAA, never in 1..39
  // pden needs no init: every entry written unconditionally each launch

  // 64 blocks of 16 waves, 1 block/CU: trivially co-resident on 256 CUs
  fps_den_kernel<<<dim3(NB * BPB), dim3(TPB), 0, stream>>>(pcs, slots, pden);
  var_kernel<<<dim3(1), dim3(TPB), 0, stream>>>(pden, out);
}

// Round 10
// 184.322 us; speedup vs baseline: 3.0623x; 3.0084x over previous
//
#include <hip/hip_runtime.h>

typedef unsigned long long ull;

#define NB    16      // batches
#define NPTS  65536   // points per batch
#define NSEED 40      // seeds
#define BPB   16      // blocks per batch (R6-verified best)
#define TPB   1024    // threads per block (16 waves)
#define NW    16      // waves per block
#define PPT   4       // points per thread
#define R2    0.0025f // RADIUS^2
#define PAYLOAD 0xFFFFFFFFFFFFull

// pack (value, index): unsigned max == (max value, then smallest index)
__device__ __forceinline__ ull packdi(float v, int idx) {
  return ((ull)__float_as_uint(v) << 16) | (ull)((unsigned)(idx ^ 0xFFFF) & 0xFFFFu);
}

__global__ __launch_bounds__(TPB, 4) void fps_den_kernel(
    const float* __restrict__ pcs, ull* __restrict__ slots, float* __restrict__ pden)
{
  const int beta = blockIdx.x >> 4;   // batch
  const int blk  = blockIdx.x & 15;   // block within batch
  const int tid  = threadIdx.x;
  const int lane = tid & 63;
  const int wav  = tid >> 6;
  const float* __restrict__ base = pcs + (size_t)beta * (NPTS * 3);

  __shared__ ull   sRedP[2][NW];                    // parity-buffered wave winners
  __shared__ float sRedX[2][NW], sRedY[2][NW], sRedZ[2][NW];
  __shared__ float sWx[2], sWy[2], sWz[2];          // parity-buffered round winner
  __shared__ float sSx[NSEED], sSy[NSEED], sSz[NSEED];  // seed history (wave-0 tail)
  __shared__ float sDen[NW][NSEED];                 // per-wave density partials

  // register-resident points + running min-distance
  float px[PPT], py[PPT], pz[PPT], dist[PPT];
#pragma unroll
  for (int j = 0; j < PPT; ++j) {
    int n = blk * (TPB * PPT) + j * TPB + tid;
    px[j] = base[n * 3 + 0];
    py[j] = base[n * 3 + 1];
    pz[j] = base[n * 3 + 2];
    dist[j] = 1e10f;
  }

  float cx = base[0], cy = base[1], cz = base[2];   // seed 0 = point 0
  if (tid == 0) { sSx[0] = cx; sSy[0] = cy; sSz[0] = cz; }

  // record layout: [beta][parity][blk][word], word w = (gen<<48) | payload_w
  //   w0: dist/idx packed (48b)   w1: x bits   w2: y bits   w3: z bits
  ull* myslots = slots + (size_t)beta * (2 * BPB * 4);

  for (int k = 0; k < NSEED - 1; ++k) {
    // ---- min-update + thread-local argmax ----
    ull bestp = 0; float bx = 0.f, by = 0.f, bz = 0.f;
#pragma unroll
    for (int j = 0; j < PPT; ++j) {
      float dx = px[j] - cx, dy = py[j] - cy, dz = pz[j] - cz;
      // match numpy: round each square, sum as (d0+d1)+d2, no FMA contraction
      float d  = __fadd_rn(__fadd_rn(__fmul_rn(dx, dx), __fmul_rn(dy, dy)),
                           __fmul_rn(dz, dz));
      float nd = fminf(dist[j], d);
      dist[j]  = nd;
      int n    = blk * (TPB * PPT) + j * TPB + tid;
      ull p    = packdi(nd, n);
      if (p > bestp) { bestp = p; bx = px[j]; by = py[j]; bz = pz[j]; }
    }
    // KEY-ONLY butterfly (1 ull shfl/level), then single coord fetch from winner
    ull mx = bestp;
#pragma unroll
    for (int o = 32; o > 0; o >>= 1) {
      ull q = __shfl_xor(mx, o, 64);
      mx = mx > q ? mx : q;
    }
    ull bal = __ballot(bestp == mx);          // packed keys unique (idx in low bits)
    int src = __ffsll((long long)bal) - 1;
    float gx = __shfl(bx, src, 64);
    float gy = __shfl(by, src, 64);
    float gz = __shfl(bz, src, 64);
    if (lane == 0) {
      sRedP[k & 1][wav] = mx;
      sRedX[k & 1][wav] = gx; sRedY[k & 1][wav] = gy; sRedZ[k & 1][wav] = gz;
    }
    __syncthreads();   // barrier 1: sRed complete

    const ull gen = (ull)(k + 1);
    const ull g48 = gen << 48;
    ull* arr = myslots + (size_t)((k + 1) & 1) * (BPB * 4);

    if (wav == 0) {
      // ---- wave 0: pure exchange, nothing else on the critical path ----
      ull rp = (lane < NW) ? sRedP[k & 1][lane] : 0;
      ull m2 = rp;
#pragma unroll
      for (int o = 8; o > 0; o >>= 1) {     // masks <16: lanes 0..15 closed group
        ull q = __shfl_xor(m2, o, 64);
        m2 = m2 > q ? m2 : q;
      }
      ull bal2 = __ballot((rp == m2) && (lane < NW));
      int s2 = __ffsll((long long)bal2) - 1;          // wave-uniform
      float rx = sRedX[k & 1][s2];                    // broadcast LDS reads
      float ry = sRedY[k & 1][s2];
      float rz = sRedZ[k & 1][s2];
      ull rec = g48 | (m2 & PAYLOAD);
      if (lane == 1) rec = g48 | (ull)__float_as_uint(rx);
      if (lane == 2) rec = g48 | (ull)__float_as_uint(ry);
      if (lane == 3) rec = g48 | (ull)__float_as_uint(rz);
      if (lane < 4)
        __hip_atomic_store(&arr[blk * 4 + lane], rec,
                           __ATOMIC_RELAXED, __HIP_MEMORY_SCOPE_AGENT);

      // 2-deep pipelined poll: issue next load BEFORE checking current one —
      // failed-check cost drops from (latency+check) to ~latency/2
      ull vcur = __hip_atomic_load(&arr[lane], __ATOMIC_RELAXED,
                                   __HIP_MEMORY_SCOPE_AGENT);
      for (;;) {
        ull vnext = __hip_atomic_load(&arr[lane], __ATOMIC_RELAXED,
                                      __HIP_MEMORY_SCOPE_AGENT);
        if (__all((int)((vcur >> 48) == gen))) break;
        vcur = vnext;
      }
      // extract winner from vcur (16 slots x 4 words, lane i holds word i)
      ull pl = ((lane & 3) == 0) ? (vcur & PAYLOAD) : 0;
      ull m = pl;
#pragma unroll
      for (int o = 32; o > 0; o >>= 1) {
        ull q = __shfl_xor(m, o, 64);
        m = m > q ? m : q;
      }
      ull balw = __ballot((pl == m) && ((lane & 3) == 0));
      int srcw = __ffsll((long long)balw) - 1;        // winner's word-0 lane
      float f   = __uint_as_float((unsigned)(vcur & 0xFFFFFFFFull));
      float wx2 = __shfl(f, srcw + 1, 64);
      float wy2 = __shfl(f, srcw + 2, 64);
      float wz2 = __shfl(f, srcw + 3, 64);
      if (lane == 0) {
        sWx[k & 1] = wx2; sWy[k & 1] = wy2; sWz[k & 1] = wz2;
        sSx[k + 1] = wx2; sSy[k + 1] = wy2; sSz[k + 1] = wz2;
      }
    } else {
      // ---- waves 1..15: density for CURRENT seed, hidden in exchange window ----
      float da = 0.f;
#pragma unroll
      for (int j = 0; j < PPT; ++j) {
        float dx = px[j] - cx, dy = py[j] - cy, dz = pz[j] - cz;
        float d  = dx * dx + dy * dy + dz * dz;
        da += fmaxf(R2 - d, 0.f);
      }
#pragma unroll
      for (int o = 32; o > 0; o >>= 1) da += __shfl_xor(da, o, 64);
      if (lane == 0) sDen[wav][k] = da;
    }
    __syncthreads();   // barrier 2: winner published
    cx = sWx[k & 1]; cy = sWy[k & 1]; cz = sWz[k & 1];
  }

  // ---- tails ----
  if (wav == 0) {
    // wave 0's density for ALL seeds, replayed from LDS (off the critical path)
    for (int s = 0; s < NSEED; ++s) {
      float sx = sSx[s], sy = sSy[s], sz = sSz[s];
      float a = 0.f;
#pragma unroll
      for (int j = 0; j < PPT; ++j) {
        float dx = px[j] - sx, dy = py[j] - sy, dz = pz[j] - sz;
        float d  = dx * dx + dy * dy + dz * dz;
        a += fmaxf(R2 - d, 0.f);
      }
#pragma unroll
      for (int o = 32; o > 0; o >>= 1) a += __shfl_xor(a, o, 64);
      if (lane == 0) sDen[0][s] = a;
    }
  } else {
    // waves 1..15: last seed (c_39) — cx holds it after the loop
    float a = 0.f;
#pragma unroll
    for (int j = 0; j < PPT; ++j) {
      float dx = px[j] - cx, dy = py[j] - cy, dz = pz[j] - cz;
      float d  = dx * dx + dy * dy + dz * dz;
      a += fmaxf(R2 - d, 0.f);
    }
#pragma unroll
    for (int o = 32; o > 0; o >>= 1) a += __shfl_xor(a, o, 64);
    if (lane == 0) sDen[wav][NSEED - 1] = a;
  }
  __syncthreads();

  if (tid < NSEED) {   // per-block density partial, plain stores
    float t = 0.f;
#pragma unroll
    for (int w = 0; w < NW; ++w) t += sDen[w][tid];
    pden[((size_t)beta * BPB + blk) * NSEED + tid] = t;
  }
}

__global__ void var_kernel(const float* __restrict__ pden, float* __restrict__ out) {
  __shared__ float sD[NB][NSEED];
  __shared__ float sV[NB];
  int t = threadIdx.x;
  if (t < NB * NSEED) {
    int beta = t / NSEED, s = t - beta * NSEED;
    float a = 0.f;
#pragma unroll
    for (int b = 0; b < BPB; ++b) a += pden[((size_t)beta * BPB + b) * NSEED + s];
    sD[beta][s] = a;
  }
  __syncthreads();
  if (t < NB) {
    float m = 0.f;
    for (int s = 0; s < NSEED; ++s) m += sD[t][s];
    m /= (float)NSEED;
    float q = 0.f;
    for (int s = 0; s < NSEED; ++s) { float d = sD[t][s] - m; q += d * d; }
    sV[t] = q / (float)(NSEED - 1);   // ddof=1
  }
  __syncthreads();
  if (t == 0) {
    float v = 0.f;
    for (int i = 0; i < NB; ++i) v += sV[i];
    out[0] = v / (float)NB;
  }
}

extern "C" void kernel_launch(void* const* d_in, const int* in_sizes, int n_in,
                              void* d_out, int out_size, void* d_ws, size_t ws_size,
                              hipStream_t stream) {
  const float* pcs = (const float*)d_in[0];
  float* out  = (float*)d_out;
  float* pden = (float*)d_ws;                       // 16*16*40*4 = 40960 B
  ull*   slots = (ull*)((char*)d_ws + 40960);       // 16*2*16*4*8 = 16384 B
  // slots need no init: poisoned 0xAA.. gives gen tag 0xAAAA, never in 1..39
  // pden needs no init: every entry written unconditionally each launch

  fps_den_kernel<<<dim3(NB * BPB), dim3(TPB), 0, stream>>>(pcs, slots, pden);
  var_kernel<<<dim3(1), dim3(TPB), 0, stream>>>(pden, out);
}

// Round 11
// 183.998 us; speedup vs baseline: 3.0677x; 1.0018x over previous
//
#include <hip/hip_runtime.h>

typedef unsigned long long ull;

#define NB    16      // batches
#define NPTS  65536   // points per batch
#define NSEED 40      // seeds
#define BPB   16      // blocks per batch
#define TPB   1024    // threads per block (16 waves)
#define NW    16      // waves per block
#define PPT   4       // points per thread
#define R2    0.0025f // RADIUS^2
#define PAYLOAD 0xFFFFFFFFFFFFull
#define DONEG 40ull   // pden tag: != poison 0xAAAA, != gens 1..39

// pack (value, index): unsigned max == (max value, then smallest index)
__device__ __forceinline__ ull packdi(float v, int idx) {
  return ((ull)__float_as_uint(v) << 16) | (ull)((unsigned)(idx ^ 0xFFFF) & 0xFFFFu);
}

__global__ __launch_bounds__(TPB, 4) void fps_den_kernel(
    const float* __restrict__ pcs, ull* __restrict__ slots,
    ull* __restrict__ pden, float* __restrict__ out)
{
  const int beta = blockIdx.x >> 4;   // batch
  const int blk  = blockIdx.x & 15;   // block within batch
  const int tid  = threadIdx.x;
  const int lane = tid & 63;
  const int wav  = tid >> 6;
  const float* __restrict__ base = pcs + (size_t)beta * (NPTS * 3);

  __shared__ ull   sRedP[2][NW];                    // parity-buffered wave winners
  __shared__ float sRedX[2][NW], sRedY[2][NW], sRedZ[2][NW];
  __shared__ float sWx[2], sWy[2], sWz[2];          // parity-buffered round winner
  __shared__ float sSx[NSEED], sSy[NSEED], sSz[NSEED];  // seed history (wave-0 tail)
  __shared__ float sDen[NW][NSEED];                 // density partials / agg reuse
  __shared__ float sV[NB];

  // register-resident points + running min-distance
  float px[PPT], py[PPT], pz[PPT], dist[PPT];
#pragma unroll
  for (int j = 0; j < PPT; ++j) {
    int n = blk * (TPB * PPT) + j * TPB + tid;
    px[j] = base[n * 3 + 0];
    py[j] = base[n * 3 + 1];
    pz[j] = base[n * 3 + 2];
    dist[j] = 1e10f;
  }

  float cx = base[0], cy = base[1], cz = base[2];   // seed 0 = point 0
  if (tid == 0) { sSx[0] = cx; sSy[0] = cy; sSz[0] = cz; }

  // record layout: [beta][parity][blk][word], word w = (gen<<48) | payload_w
  //   w0: dist/idx packed (48b)   w1: x bits   w2: y bits   w3: z bits
  ull* myslots = slots + (size_t)beta * (2 * BPB * 4);

  for (int k = 0; k < NSEED - 1; ++k) {
    // ---- min-update + thread-local argmax ----
    ull bestp = 0; float bx = 0.f, by = 0.f, bz = 0.f;
#pragma unroll
    for (int j = 0; j < PPT; ++j) {
      float dx = px[j] - cx, dy = py[j] - cy, dz = pz[j] - cz;
      // match numpy: round each square, sum as (d0+d1)+d2, no FMA contraction
      float d  = __fadd_rn(__fadd_rn(__fmul_rn(dx, dx), __fmul_rn(dy, dy)),
                           __fmul_rn(dz, dz));
      float nd = fminf(dist[j], d);
      dist[j]  = nd;
      int n    = blk * (TPB * PPT) + j * TPB + tid;
      ull p    = packdi(nd, n);
      if (p > bestp) { bestp = p; bx = px[j]; by = py[j]; bz = pz[j]; }
    }
    // KEY-ONLY butterfly, then single coord fetch from winner lane
    ull mx = bestp;
#pragma unroll
    for (int o = 32; o > 0; o >>= 1) {
      ull q = __shfl_xor(mx, o, 64);
      mx = mx > q ? mx : q;
    }
    ull bal = __ballot(bestp == mx);          // packed keys unique (idx in low bits)
    int src = __ffsll((long long)bal) - 1;
    float gx = __shfl(bx, src, 64);
    float gy = __shfl(by, src, 64);
    float gz = __shfl(bz, src, 64);
    if (lane == 0) {
      sRedP[k & 1][wav] = mx;
      sRedX[k & 1][wav] = gx; sRedY[k & 1][wav] = gy; sRedZ[k & 1][wav] = gz;
    }
    __syncthreads();   // barrier 1: sRed complete

    const ull gen = (ull)(k + 1);
    const ull g48 = gen << 48;
    ull* arr = myslots + (size_t)((k + 1) & 1) * (BPB * 4);

    if (wav == 0) {
      // ---- wave 0: pure exchange ----
      ull rp = (lane < NW) ? sRedP[k & 1][lane] : 0;
      ull m2 = rp;
#pragma unroll
      for (int o = 8; o > 0; o >>= 1) {
        ull q = __shfl_xor(m2, o, 64);
        m2 = m2 > q ? m2 : q;
      }
      ull bal2 = __ballot((rp == m2) && (lane < NW));
      int s2 = __ffsll((long long)bal2) - 1;          // wave-uniform
      float rx = sRedX[k & 1][s2];                    // broadcast LDS reads
      float ry = sRedY[k & 1][s2];
      float rz = sRedZ[k & 1][s2];
      ull rec = g48 | (m2 & PAYLOAD);
      if (lane == 1) rec = g48 | (ull)__float_as_uint(rx);
      if (lane == 2) rec = g48 | (ull)__float_as_uint(ry);
      if (lane == 3) rec = g48 | (ull)__float_as_uint(rz);
      if (lane < 4)
        __hip_atomic_store(&arr[blk * 4 + lane], rec,
                           __ATOMIC_RELAXED, __HIP_MEMORY_SCOPE_AGENT);

      // 2-deep pipelined poll
      ull vcur = __hip_atomic_load(&arr[lane], __ATOMIC_RELAXED,
                                   __HIP_MEMORY_SCOPE_AGENT);
      for (;;) {
        ull vnext = __hip_atomic_load(&arr[lane], __ATOMIC_RELAXED,
                                      __HIP_MEMORY_SCOPE_AGENT);
        if (__all((int)((vcur >> 48) == gen))) break;
        vcur = vnext;
      }
      ull pl = ((lane & 3) == 0) ? (vcur & PAYLOAD) : 0;
      ull m = pl;
#pragma unroll
      for (int o = 32; o > 0; o >>= 1) {
        ull q = __shfl_xor(m, o, 64);
        m = m > q ? m : q;
      }
      ull balw = __ballot((pl == m) && ((lane & 3) == 0));
      int srcw = __ffsll((long long)balw) - 1;        // winner's word-0 lane
      float f   = __uint_as_float((unsigned)(vcur & 0xFFFFFFFFull));
      float wx2 = __shfl(f, srcw + 1, 64);
      float wy2 = __shfl(f, srcw + 2, 64);
      float wz2 = __shfl(f, srcw + 3, 64);
      if (lane == 0) {
        sWx[k & 1] = wx2; sWy[k & 1] = wy2; sWz[k & 1] = wz2;
        sSx[k + 1] = wx2; sSy[k + 1] = wy2; sSz[k + 1] = wz2;
      }
    } else {
      // ---- waves 1..15: density for CURRENT seed, hidden in exchange window ----
      float da = 0.f;
#pragma unroll
      for (int j = 0; j < PPT; ++j) {
        float dx = px[j] - cx, dy = py[j] - cy, dz = pz[j] - cz;
        float d  = dx * dx + dy * dy + dz * dz;
        da += fmaxf(R2 - d, 0.f);
      }
#pragma unroll
      for (int o = 32; o > 0; o >>= 1) da += __shfl_xor(da, o, 64);
      if (lane == 0) sDen[wav][k] = da;
    }
    __syncthreads();   // barrier 2: winner published
    cx = sWx[k & 1]; cy = sWy[k & 1]; cz = sWz[k & 1];
  }

  // ---- density tails ----
  if (wav == 0) {
    for (int s = 0; s < NSEED; ++s) {   // wave 0: all seeds, replayed from LDS
      float sx = sSx[s], sy = sSy[s], sz = sSz[s];
      float a = 0.f;
#pragma unroll
      for (int j = 0; j < PPT; ++j) {
        float dx = px[j] - sx, dy = py[j] - sy, dz = pz[j] - sz;
        float d  = dx * dx + dy * dy + dz * dz;
        a += fmaxf(R2 - d, 0.f);
      }
#pragma unroll
      for (int o = 32; o > 0; o >>= 1) a += __shfl_xor(a, o, 64);
      if (lane == 0) sDen[0][s] = a;
    }
  } else {
    float a = 0.f;                      // waves 1..15: last seed (cx = c_39)
#pragma unroll
    for (int j = 0; j < PPT; ++j) {
      float dx = px[j] - cx, dy = py[j] - cy, dz = pz[j] - cz;
      float d  = dx * dx + dy * dy + dz * dz;
      a += fmaxf(R2 - d, 0.f);
    }
#pragma unroll
    for (int o = 32; o > 0; o >>= 1) a += __shfl_xor(a, o, 64);
    if (lane == 0) sDen[wav][NSEED - 1] = a;
  }
  __syncthreads();

  // ---- publish per-block density partials as gen-tagged, self-validating words
  if (tid < NSEED) {
    float t = 0.f;
#pragma unroll
    for (int w = 0; w < NW; ++w) t += sDen[w][tid];
    ull rec = (DONEG << 48) | (ull)__float_as_uint(t);
    __hip_atomic_store(&pden[((size_t)beta * BPB + blk) * NSEED + tid], rec,
                       __ATOMIC_RELAXED, __HIP_MEMORY_SCOPE_AGENT);
  }

  // ---- block 0: fused variance epilogue (saves the second dispatch) ----
  if (blockIdx.x == 0) {
    __syncthreads();   // barrier drains vmcnt: own pden stores are committed
    if (tid < NB * NSEED) {
      int b0 = tid / NSEED, s = tid - b0 * NSEED;   // (batch, seed)
      float a = 0.f;
#pragma unroll
      for (int c = 0; c < 2; ++c) {                 // 2 chunks of 8 pipelined loads
        ull v[8];
#pragma unroll
        for (int b = 0; b < 8; ++b)
          v[b] = __hip_atomic_load(
              &pden[((size_t)b0 * BPB + c * 8 + b) * NSEED + s],
              __ATOMIC_RELAXED, __HIP_MEMORY_SCOPE_AGENT);
        for (;;) {                                   // retry only invalid words
          bool ok = true;
#pragma unroll
          for (int b = 0; b < 8; ++b)
            if ((v[b] >> 48) != DONEG) {
              ok = false;
              v[b] = __hip_atomic_load(
                  &pden[((size_t)b0 * BPB + c * 8 + b) * NSEED + s],
                  __ATOMIC_RELAXED, __HIP_MEMORY_SCOPE_AGENT);
            }
          if (ok) break;
        }
#pragma unroll
        for (int b = 0; b < 8; ++b)
          a += __uint_as_float((unsigned)(v[b] & 0xFFFFFFFFull));
      }
      sDen[b0][s] = a;   // reuse sDen as the 16x40 density matrix
    }
    __syncthreads();
    if (tid < NB) {
      float m = 0.f;
      for (int s = 0; s < NSEED; ++s) m += sDen[tid][s];
      m /= (float)NSEED;
      float q = 0.f;
      for (int s = 0; s < NSEED; ++s) { float d = sDen[tid][s] - m; q += d * d; }
      sV[tid] = q / (float)(NSEED - 1);   // ddof=1
    }
    __syncthreads();
    if (tid == 0) {
      float v = 0.f;
      for (int i = 0; i < NB; ++i) v += sV[i];
      out[0] = v / (float)NB;
    }
  }
}

extern "C" void kernel_launch(void* const* d_in, const int* in_sizes, int n_in,
                              void* d_out, int out_size, void* d_ws, size_t ws_size,
                              hipStream_t stream) {
  const float* pcs = (const float*)d_in[0];
  float* out  = (float*)d_out;
  ull*   pden = (ull*)d_ws;                         // 16*16*40*8 = 81920 B
  ull*   slots = (ull*)((char*)d_ws + 81920);       // 16*2*16*4*8 = 16384 B
  // no init needed: poison 0xAA.. gives tag 0xAAAA, never in {1..39, 40}
  // until written this launch; every word written unconditionally each launch

  fps_den_kernel<<<dim3(NB * BPB), dim3(TPB), 0, stream>>>(pcs, slots, pden, out);
}